// Round 6
// baseline (254.964 us; speedup 1.0000x reference)
//
#include <hip/hip_runtime.h>
#include <stdint.h>

// GaitnetActor B=8192, OPT=16. Round 23: merge k_conv into k_cse (2 launches
// instead of 3). k_cse now converts its B-operands (sw2, tw1se) inline from
// fp32 with native RNE casts (bit-identical to the old pre-conversion), so
// those weights are never pre-converted; the remaining conv work (tw1ue,
// tw2, uw2, uw1b = 54272 ushort4 items) folds into k_cse as a 106-item
// per-block prologue. Saves one launch gap + k_conv's serial ~8us, costs
// ~+4us of doubled (fp32) B-bytes in k_cse. k_main unchanged from R22
// (133us band, native f2u).
// out[0:131072]=logits fp32, [131072:262144]=duration fp32.

static constexpr int B_ = 8192;

typedef __attribute__((ext_vector_type(8))) short bf16x8;
typedef __attribute__((ext_vector_type(4))) float f32x4;

__device__ __forceinline__ float u2f(uint16_t u) {
    union { uint32_t i; float f; } c; c.i = (uint32_t)u << 16; return c.f;
}
__device__ __forceinline__ uint16_t f2u(float f) {
    __bf16 b = (__bf16)f;                       // native RNE cvt on gfx950
    return __builtin_bit_cast(uint16_t, b);
}
__device__ __forceinline__ bf16x8 cvt8(float4 a, float4 b) {
    bf16x8 r;
    r[0] = (short)f2u(a.x); r[1] = (short)f2u(a.y);
    r[2] = (short)f2u(a.z); r[3] = (short)f2u(a.w);
    r[4] = (short)f2u(b.x); r[5] = (short)f2u(b.y);
    r[6] = (short)f2u(b.z); r[7] = (short)f2u(b.w);
    return r;
}

// ws layout (uint16 elems). WTW1SE/WSW2 regions now unused (inline fp32).
static constexpr size_t WCSE   = 0;                    // bf16 [8192][512]
static constexpr size_t WTW1SE = 4194304;              // (unused)
static constexpr size_t WTW1UE = WTW1SE + 131072;      // bf16 [512][128]
static constexpr size_t WTW2   = WTW1UE + 65536;       // bf16 [256][512]
static constexpr size_t WUW2   = WTW2 + 131072;        // bf16 [128][128]
static constexpr size_t WSW2   = WUW2 + 16384;         // (unused)
static constexpr size_t WUW1B  = WSW2 + 65536;         // bf16 [128][32] 0-pad

// -------- k_cse_conv: conv share + se + cse, 16 elems/block (512 blocks) ---
__global__ __launch_bounds__(512) void k_cse_conv(
    const float* __restrict__ obs,
    const float* __restrict__ sw1, const float* __restrict__ sb1,
    const float* __restrict__ sw2, const float* __restrict__ sb2,
    const float* __restrict__ tw1, const float* __restrict__ tb1,
    const float* __restrict__ tw2, const float* __restrict__ uw2,
    const float* __restrict__ uw1,
    uint16_t* __restrict__ ws)
{
    __shared__ float xs[16][24];
    __shared__ uint16_t h1s[16 * 264];
    __shared__ uint16_t seL[16 * 264];
    const int t = threadIdx.x;
    const int b0 = blockIdx.x * 16;

    // ---- conv share: 106 ushort4 items per block (512*106 = 54272) ----
    if (t < 106) {
        int j = blockIdx.x * 106 + t;
        if (j < 16384) {                         // tw1 ue-part (k>=256)
            int n = j >> 5, w = j & 31;
            float4 v = *reinterpret_cast<const float4*>(
                tw1 + (size_t)n * 384 + 256 + w * 4);
            ushort4 o;
            o.x = f2u(v.x); o.y = f2u(v.y); o.z = f2u(v.z); o.w = f2u(v.w);
            *reinterpret_cast<ushort4*>(ws + WTW1UE + (size_t)n * 128 + w * 4) = o;
        } else if (j < 49152) {                  // tw2
            int q = (j - 16384) * 4;
            float4 v = *reinterpret_cast<const float4*>(tw2 + q);
            ushort4 o;
            o.x = f2u(v.x); o.y = f2u(v.y); o.z = f2u(v.z); o.w = f2u(v.w);
            *reinterpret_cast<ushort4*>(ws + WTW2 + q) = o;
        } else if (j < 53248) {                  // uw2
            int q = (j - 49152) * 4;
            float4 v = *reinterpret_cast<const float4*>(uw2 + q);
            ushort4 o;
            o.x = f2u(v.x); o.y = f2u(v.y); o.z = f2u(v.z); o.w = f2u(v.w);
            *reinterpret_cast<ushort4*>(ws + WUW2 + q) = o;
        } else {                                 // uw1b: zero-padded K=32
            int q = j - 53248;                   // [0,1024)
            int n = q >> 3, k0 = (q & 7) * 4;
            ushort4 o = {0, 0, 0, 0};
            if (k0 < 8) {
                float4 v = *reinterpret_cast<const float4*>(uw1 + n * 8 + k0);
                o.x = f2u(v.x); o.y = f2u(v.y); o.z = f2u(v.z); o.w = f2u(v.w);
            }
            *reinterpret_cast<ushort4*>(ws + WUW1B + n * 32 + k0) = o;
        }
    }

    if (t < 352) {
        int e = t / 22, c = t - e * 22;
        xs[e][c] = obs[(size_t)(b0 + e) * 150 + c];
    }
    __syncthreads();
    {   // shared L1 (VALU): neuron t&255, 8 elems each
        const int n = t & 255;
        float w[22];
        #pragma unroll
        for (int k = 0; k < 22; ++k) w[k] = sw1[n * 22 + k];
        const float bias = sb1[n];
        #pragma unroll
        for (int ii = 0; ii < 8; ++ii) {
            int e = (t >> 8) * 8 + ii;
            float a = bias;
            #pragma unroll
            for (int k = 0; k < 22; ++k) a += w[k] * xs[e][k];
            h1s[e * 264 + n] = f2u(fmaxf(a, 0.f));
        }
    }
    __syncthreads();
    const int wv = t >> 6, lane = t & 63, quad = lane >> 4, l16 = lane & 15;
    {   // shared L2 (MFMA): M=16, wave N=32, K=256, B = fp32 sw2 inline ----
        f32x4 acc[2];
        #pragma unroll
        for (int nt = 0; nt < 2; ++nt) {
            float bv = sb2[wv * 32 + nt * 16 + l16];
            acc[nt] = {bv, bv, bv, bv};
        }
        const float* bb = sw2 + (size_t)(wv * 32 + l16) * 256 + quad * 8;
        #pragma unroll
        for (int kk = 0; kk < 8; ++kk) {
            bf16x8 af = *reinterpret_cast<const bf16x8*>(
                &h1s[l16 * 264 + kk * 32 + quad * 8]);
            #pragma unroll
            for (int nt = 0; nt < 2; ++nt) {
                const float* p = bb + nt * 4096 + kk * 32;
                float4 a = *reinterpret_cast<const float4*>(p);
                float4 b = *reinterpret_cast<const float4*>(p + 4);
                acc[nt] = __builtin_amdgcn_mfma_f32_16x16x32_bf16(
                    af, cvt8(a, b), acc[nt], 0, 0, 0);
            }
        }
        #pragma unroll
        for (int nt = 0; nt < 2; ++nt)
            #pragma unroll
            for (int r = 0; r < 4; ++r)
                seL[(quad * 4 + r) * 264 + wv * 32 + nt * 16 + l16] =
                    f2u(fmaxf(acc[nt][r], 0.f));
    }
    __syncthreads();
    {   // cse (MFMA): M=16, wave N=64, K=256, B = fp32 tw1[:, :256] inline,
        // two nt-halves to bound fp32 staging registers
        const float* bb = tw1 + (size_t)(wv * 64 + l16) * 384 + quad * 8;
        #pragma unroll
        for (int h = 0; h < 2; ++h) {
            f32x4 acc[2];
            #pragma unroll
            for (int nt2 = 0; nt2 < 2; ++nt2) {
                float bv = tb1[wv * 64 + (h * 2 + nt2) * 16 + l16];
                acc[nt2] = {bv, bv, bv, bv};
            }
            #pragma unroll
            for (int kk = 0; kk < 8; ++kk) {
                bf16x8 af = *reinterpret_cast<const bf16x8*>(
                    &seL[l16 * 264 + kk * 32 + quad * 8]);
                #pragma unroll
                for (int nt2 = 0; nt2 < 2; ++nt2) {
                    const float* p = bb + (size_t)(h * 2 + nt2) * 6144 + kk * 32;
                    float4 a = *reinterpret_cast<const float4*>(p);
                    float4 b = *reinterpret_cast<const float4*>(p + 4);
                    acc[nt2] = __builtin_amdgcn_mfma_f32_16x16x32_bf16(
                        af, cvt8(a, b), acc[nt2], 0, 0, 0);
                }
            }
            #pragma unroll
            for (int nt2 = 0; nt2 < 2; ++nt2)
                #pragma unroll
                for (int r = 0; r < 4; ++r)
                    ws[WCSE + (size_t)(b0 + quad * 4 + r) * 512 +
                       wv * 64 + (h * 2 + nt2) * 16 + l16] = f2u(acc[nt2][r]);
        }
    }
}

// ---------------- k_main (R12 structure, native cvt) -----------------------
// LDS (bytes): uqb bf16[64][40] 0..5120 | noop f32[64] @5120 | cse bf16[4][512]
// @5376 | h1u bf16[64][136] @9472 | uet @26880 | h1t bf16[64][264] @44288
// (t2 overlays) -> 78080 B, 2 blocks/CU.
static constexpr int UQB_OFF  = 0;
static constexpr int NOOP_OFF = 5120;
static constexpr int CSE_OFF  = 5376;
static constexpr int H1U_OFF  = 9472;
static constexpr int UET_OFF  = 26880;
static constexpr int H1T_OFF  = 44288;
static constexpr int SMEM_SZ  = 78080;

__global__ __launch_bounds__(512, 4) void k_main(
    const float* __restrict__ obs,
    const float* __restrict__ ub1,
    const float* __restrict__ ub2, const float* __restrict__ emb,
    const float* __restrict__ tb2,
    const float* __restrict__ vw,  const float* __restrict__ vb,
    const float* __restrict__ dw,  const float* __restrict__ db,
    const uint16_t* __restrict__ wsb,
    float* __restrict__ out)
{
    __shared__ __align__(16) char smem[SMEM_SZ];
    uint16_t* uqb   = (uint16_t*)(smem + UQB_OFF);
    float*    noopf = (float*)(smem + NOOP_OFF);
    uint16_t* cseL  = (uint16_t*)(smem + CSE_OFF);
    uint16_t* h1u   = (uint16_t*)(smem + H1U_OFF);
    uint16_t* uet   = (uint16_t*)(smem + UET_OFF);
    uint16_t* h1t   = (uint16_t*)(smem + H1T_OFF);
    uint16_t* t2    = h1t;

    const int t    = threadIdx.x;
    const int wv   = t >> 6;
    const int lane = t & 63;
    const int quad = lane >> 4;
    const int l16  = lane & 15;
    const int b0   = blockIdx.x * 4;

    const uint16_t* csep  = wsb + WCSE;
    const uint16_t* tw1ue = wsb + WTW1UE;
    const uint16_t* tw2b  = wsb + WTW2;
    const uint16_t* uw2b  = wsb + WUW2;
    const uint16_t* uw1b  = wsb + WUW1B;

    // ---- stage 1: uqb bf16 [64][40] (K=32 zero-padded), noop, cse rows ----
    {
        int r = t >> 3, q = t & 7;               // row 0..63, k-quad 0..7
        int e = r >> 4, o = r & 15;
        ushort4 ov = {0, 0, 0, 0};
        if (q < 2) {                             // cols 0..7 real (8B-aligned)
            const float2* sp = reinterpret_cast<const float2*>(
                &obs[(size_t)(b0 + e) * 150 + 22 + o * 8 + q * 4]);
            float2 a = sp[0], b = sp[1];
            ov.x = f2u(a.x); ov.y = f2u(a.y); ov.z = f2u(b.x); ov.w = f2u(b.y);
        }
        *reinterpret_cast<ushort4*>(&uqb[r * 40 + q * 4]) = ov;
        #pragma unroll
        for (int ii = 0; ii < 2; ++ii) {         // cse rows: 1024 dwords
            int i = t + ii * 512;
            int ee = i >> 8, cc = i & 255;
            ((uint32_t*)cseL)[ee * 256 + cc] =
                ((const uint32_t*)(csep + (size_t)(b0 + ee) * 512))[cc];
        }
        if (t < 64) {
            int ee = t >> 4, oo = t & 15;
            noopf[t] = (obs[(size_t)(b0 + ee) * 150 + 22 + oo * 8] == 1.0f) ? 1.0f : 0.0f;
        }
    }
    __syncthreads();

    // ---- stage 2: unique L1 via MFMA (wave: M=64 x N=16, K=32) ----
    {
        const int n = wv * 16 + l16;
        const float bv = ub1[n];
        f32x4 acc[4];
        #pragma unroll
        for (int mt = 0; mt < 4; ++mt) acc[mt] = {bv, bv, bv, bv};
        bf16x8 bf = *reinterpret_cast<const bf16x8*>(&uw1b[n * 32 + quad * 8]);
        #pragma unroll
        for (int mt = 0; mt < 4; ++mt) {
            bf16x8 af = *reinterpret_cast<const bf16x8*>(
                &uqb[(mt * 16 + l16) * 40 + quad * 8]);
            acc[mt] = __builtin_amdgcn_mfma_f32_16x16x32_bf16(af, bf, acc[mt], 0, 0, 0);
        }
        #pragma unroll
        for (int mt = 0; mt < 4; ++mt)
            #pragma unroll
            for (int r = 0; r < 4; ++r) {
                int row = mt * 16 + quad * 4 + r;
                h1u[row * 136 + n] = f2u(fmaxf(acc[mt][r], 0.f));
            }
    }
    __syncthreads();

    // ---- stage 3: unique L2 via MFMA (wave: M=64 x N=16), K=128 -> uet ----
    {
        const int n = wv * 16 + l16;
        const float bv = ub2[n];
        const float ev = emb[n];
        f32x4 acc[4];
        #pragma unroll
        for (int mt = 0; mt < 4; ++mt) acc[mt] = {bv, bv, bv, bv};
        #pragma unroll
        for (int kk = 0; kk < 4; ++kk) {
            bf16x8 bf = *reinterpret_cast<const bf16x8*>(
                &uw2b[(size_t)n * 128 + kk * 32 + quad * 8]);
            #pragma unroll
            for (int mt = 0; mt < 4; ++mt) {
                bf16x8 af = *reinterpret_cast<const bf16x8*>(
                    &h1u[(mt * 16 + l16) * 136 + kk * 32 + quad * 8]);
                acc[mt] = __builtin_amdgcn_mfma_f32_16x16x32_bf16(af, bf, acc[mt], 0, 0, 0);
            }
        }
        #pragma unroll
        for (int mt = 0; mt < 4; ++mt)
            #pragma unroll
            for (int r = 0; r < 4; ++r) {
                int row = mt * 16 + quad * 4 + r;
                float v = (noopf[row] != 0.0f) ? ev : fmaxf(acc[mt][r], 0.f);
                uet[row * 136 + n] = f2u(v);
            }
    }
    __syncthreads();

    // ---- trunk: 2 N-chunks of 256; L1 (K=128, acc init = cse) -> L2 ----
    f32x4 acc2[4][2];
    #pragma unroll
    for (int nt = 0; nt < 2; ++nt) {
        float bv = tb2[wv * 32 + nt * 16 + l16];
        #pragma unroll
        for (int mt = 0; mt < 4; ++mt) acc2[mt][nt] = {bv, bv, bv, bv};
    }

    #pragma unroll
    for (int nc = 0; nc < 2; ++nc) {
        {
            f32x4 acc1[4][2];
            #pragma unroll
            for (int nt = 0; nt < 2; ++nt) {
                int n = nc * 256 + wv * 32 + nt * 16 + l16;
                #pragma unroll
                for (int mt = 0; mt < 4; ++mt) {
                    float v = u2f(cseL[mt * 512 + n]);
                    acc1[mt][nt] = {v, v, v, v};
                }
            }
            const uint16_t* bb = tw1ue + (size_t)(nc * 256 + wv * 32 + l16) * 128
                                 + quad * 8;
            bf16x8 bc[2], bn[2];
            bc[0] = *reinterpret_cast<const bf16x8*>(bb);
            bc[1] = *reinterpret_cast<const bf16x8*>(bb + 2048);
            #pragma unroll
            for (int kk = 0; kk < 4; ++kk) {
                if (kk < 3) {
                    bn[0] = *reinterpret_cast<const bf16x8*>(bb + (kk + 1) * 32);
                    bn[1] = *reinterpret_cast<const bf16x8*>(bb + 2048 + (kk + 1) * 32);
                }
                bf16x8 af[4];
                #pragma unroll
                for (int mt = 0; mt < 4; ++mt)
                    af[mt] = *reinterpret_cast<const bf16x8*>(
                        &uet[(mt * 16 + l16) * 136 + kk * 32 + quad * 8]);
                #pragma unroll
                for (int mt = 0; mt < 4; ++mt)
                    #pragma unroll
                    for (int nt = 0; nt < 2; ++nt)
                        acc1[mt][nt] = __builtin_amdgcn_mfma_f32_16x16x32_bf16(
                            af[mt], bc[nt], acc1[mt][nt], 0, 0, 0);
                bc[0] = bn[0]; bc[1] = bn[1];
            }
            #pragma unroll
            for (int mt = 0; mt < 4; ++mt)
                #pragma unroll
                for (int nt = 0; nt < 2; ++nt)
                    #pragma unroll
                    for (int r = 0; r < 4; ++r) {
                        int row = mt * 16 + quad * 4 + r;
                        h1t[row * 264 + wv * 32 + nt * 16 + l16] =
                            f2u(fmaxf(acc1[mt][nt][r], 0.f));
                    }
        }
        __syncthreads();
        {
            const uint16_t* cb = tw2b + (size_t)(wv * 32 + l16) * 512 + nc * 256
                                 + quad * 8;
            bf16x8 cc[2], cn[2];
            cc[0] = *reinterpret_cast<const bf16x8*>(cb);
            cc[1] = *reinterpret_cast<const bf16x8*>(cb + 8192);
            #pragma unroll
            for (int k2 = 0; k2 < 8; ++k2) {
                if (k2 < 7) {
                    cn[0] = *reinterpret_cast<const bf16x8*>(cb + (k2 + 1) * 32);
                    cn[1] = *reinterpret_cast<const bf16x8*>(cb + 8192 + (k2 + 1) * 32);
                }
                bf16x8 af[4];
                #pragma unroll
                for (int mt = 0; mt < 4; ++mt)
                    af[mt] = *reinterpret_cast<const bf16x8*>(
                        &h1t[(mt * 16 + l16) * 264 + k2 * 32 + quad * 8]);
                #pragma unroll
                for (int mt = 0; mt < 4; ++mt)
                    #pragma unroll
                    for (int nt = 0; nt < 2; ++nt)
                        acc2[mt][nt] = __builtin_amdgcn_mfma_f32_16x16x32_bf16(
                            af[mt], cc[nt], acc2[mt][nt], 0, 0, 0);
                cc[0] = cn[0]; cc[1] = cn[1];
            }
        }
        if (nc == 0) __syncthreads();
    }
    __syncthreads();
    #pragma unroll
    for (int mt = 0; mt < 4; ++mt)
        #pragma unroll
        for (int nt = 0; nt < 2; ++nt)
            #pragma unroll
            for (int r = 0; r < 4; ++r) {
                int row = mt * 16 + quad * 4 + r;
                t2[row * 264 + wv * 32 + nt * 16 + l16] =
                    f2u(fmaxf(acc2[mt][nt][r], 0.f));
            }
    __syncthreads();

    // ---- heads ----
    {
        float vwf[4], dwf[4];
        #pragma unroll
        for (int j = 0; j < 4; ++j) {
            vwf[j] = vw[lane + 64 * j];
            dwf[j] = dw[lane + 64 * j];
        }
        const float vbf = vb[0], dbf = db[0];
        #pragma unroll
        for (int rr = 0; rr < 8; ++rr) {
            int row = wv * 8 + rr;
            float sv = 0.f, sd = 0.f;
            #pragma unroll
            for (int j = 0; j < 4; ++j) {
                float tv = u2f(t2[row * 264 + lane + 64 * j]);
                sv += tv * vwf[j];
                sd += tv * dwf[j];
            }
            #pragma unroll
            for (int off = 32; off > 0; off >>= 1) {
                sv += __shfl_down(sv, off);
                sd += __shfl_down(sd, off);
            }
            if (lane == 0) {
                int g = blockIdx.x * 64 + row;
                out[g] = sv + vbf;
                float z = sd + dbf;
                float sig = 1.f / (1.f + __expf(-z));
                out[B_ * 16 + g] = sig * 0.4f + 0.1f;
            }
        }
    }
}

extern "C" void kernel_launch(void* const* d_in, const int* in_sizes, int n_in,
                              void* d_out, int out_size, void* d_ws, size_t ws_size,
                              hipStream_t stream) {
    const float* obs = (const float*)d_in[0];
    const float* sw1 = (const float*)d_in[1];
    const float* sb1 = (const float*)d_in[2];
    const float* sw2 = (const float*)d_in[3];
    const float* sb2 = (const float*)d_in[4];
    const float* uw1 = (const float*)d_in[5];
    const float* ub1 = (const float*)d_in[6];
    const float* uw2 = (const float*)d_in[7];
    const float* ub2 = (const float*)d_in[8];
    const float* emb = (const float*)d_in[9];
    const float* tw1 = (const float*)d_in[10];
    const float* tb1 = (const float*)d_in[11];
    const float* tw2 = (const float*)d_in[12];
    const float* tb2 = (const float*)d_in[13];
    const float* vw  = (const float*)d_in[14];
    const float* vb  = (const float*)d_in[15];
    const float* dw  = (const float*)d_in[16];
    const float* db  = (const float*)d_in[17];

    uint16_t* wsb = (uint16_t*)d_ws;

    k_cse_conv<<<512, 512, 0, stream>>>(obs, sw1, sb1, sw2, sb2, tw1, tb1,
                                        tw2, uw2, uw1, wsb);
    k_main<<<B_ / 4, 512, 0, stream>>>(obs, ub1, ub2, emb, tb2,
                                       vw, vb, dw, db, wsb, (float*)d_out);
}

// Round 7
// 234.241 us; speedup vs baseline: 1.0885x; 1.0885x over previous
//
#include <hip/hip_runtime.h>
#include <stdint.h>

// GaitnetActor B=8192, OPT=16. Round 24: revert R23 merge (k_cse_conv 51us:
// fp32 B doubled per-block weight bytes + cvt in MFMA inner loop; k_cse is
// weight-traffic-bound -> leave it alone). Back to R22 3-kernel structure.
// New: OPERAND-SWAPPED MFMAs in k_main. mfma(W_frag, X_frag) instead of
// (X,W): same fragments (A row=l16 <-> weight n, B col=l16 <-> batch m),
// output transposed so each lane holds 4 CONSECUTIVE neurons for one batch
// row -> f32x4 packs to one ushort4 ds_write_b64. Stores 112->28/thread,
// cvts pack, bias/cse/emb inits become contiguous float4/ushort4 loads.
// LDS read patterns and buffer contents bit-identical; heads unchanged.
// out[0:131072]=logits fp32, [131072:262144]=duration fp32.

static constexpr int B_ = 8192;

typedef __attribute__((ext_vector_type(8))) short bf16x8;
typedef __attribute__((ext_vector_type(4))) float f32x4;

__device__ __forceinline__ float u2f(uint16_t u) {
    union { uint32_t i; float f; } c; c.i = (uint32_t)u << 16; return c.f;
}
__device__ __forceinline__ uint16_t f2u(float f) {
    __bf16 b = (__bf16)f;                       // native RNE cvt on gfx950
    return __builtin_bit_cast(uint16_t, b);
}
__device__ __forceinline__ ushort4 pack4(float a, float b, float c, float d) {
    ushort4 o;
    o.x = f2u(a); o.y = f2u(b); o.z = f2u(c); o.w = f2u(d);
    return o;
}

// ws layout (uint16 elems)
static constexpr size_t WCSE   = 0;                    // bf16 [8192][512]
static constexpr size_t WTW1SE = 4194304;              // bf16 [512][256]
static constexpr size_t WTW1UE = WTW1SE + 131072;      // bf16 [512][128]
static constexpr size_t WTW2   = WTW1UE + 65536;       // bf16 [256][512]
static constexpr size_t WUW2   = WTW2 + 131072;        // bf16 [128][128]
static constexpr size_t WSW2   = WUW2 + 16384;         // bf16 [256][256]
static constexpr size_t WUW1B  = WSW2 + 65536;         // bf16 [128][32] 0-pad

// ---------------- k_conv: all weights fp32 -> bf16 (404 blocks) ------------
__global__ __launch_bounds__(256) void k_conv(
    const float* __restrict__ tw1, const float* __restrict__ tw2,
    const float* __restrict__ uw2, const float* __restrict__ sw2,
    const float* __restrict__ uw1, uint16_t* __restrict__ ws)
{
    int i4 = blockIdx.x * 256 + threadIdx.x;
    if (i4 >= 102400) {                          // uw1b: zero-padded K=32
        int q = i4 - 102400;                     // [0,1024)
        int n = q >> 3, k0 = (q & 7) * 4;
        ushort4 o = {0, 0, 0, 0};
        if (k0 < 8) {
            float4 v = *reinterpret_cast<const float4*>(uw1 + n * 8 + k0);
            o.x = f2u(v.x); o.y = f2u(v.y); o.z = f2u(v.z); o.w = f2u(v.w);
        }
        *reinterpret_cast<ushort4*>(ws + WUW1B + n * 32 + k0) = o;
        return;
    }
    const float* src; size_t dst;
    if (i4 < 32768) {                            // tw1 se-part (k<256)
        int g = i4 * 4, n = g >> 8, k = g & 255;
        src = tw1 + (size_t)n * 384 + k;
        dst = WTW1SE + (size_t)g;
    } else if (i4 < 49152) {                     // tw1 ue-part (k>=256)
        int q = i4 - 32768, n = q >> 5, w = q & 31;
        src = tw1 + (size_t)n * 384 + 256 + w * 4;
        dst = WTW1UE + (size_t)n * 128 + w * 4;
    } else if (i4 < 81920) {
        int q = (i4 - 49152) * 4;
        src = tw2 + q; dst = WTW2 + q;
    } else if (i4 < 86016) {
        int q = (i4 - 81920) * 4;
        src = uw2 + q; dst = WUW2 + q;
    } else {
        int q = (i4 - 86016) * 4;
        src = sw2 + q; dst = WSW2 + q;
    }
    float4 v = *reinterpret_cast<const float4*>(src);
    ushort4 o;
    o.x = f2u(v.x); o.y = f2u(v.y); o.z = f2u(v.z); o.w = f2u(v.w);
    *reinterpret_cast<ushort4*>(ws + dst) = o;
}

// ---------------- k_cse: se + cse, 16 elems/block, 512 thr (512 blocks) ----
__global__ __launch_bounds__(512) void k_cse(
    const float* __restrict__ obs,
    const float* __restrict__ sw1, const float* __restrict__ sb1,
    const float* __restrict__ sb2, const float* __restrict__ tb1,
    uint16_t* __restrict__ ws)
{
    __shared__ float xs[16][24];
    __shared__ uint16_t h1s[16 * 264];
    __shared__ uint16_t seL[16 * 264];
    const int t = threadIdx.x;
    const int b0 = blockIdx.x * 16;
    const uint16_t* sw2b   = ws + WSW2;
    const uint16_t* tw1seb = ws + WTW1SE;

    if (t < 352) {
        int e = t / 22, c = t - e * 22;
        xs[e][c] = obs[(size_t)(b0 + e) * 150 + c];
    }
    __syncthreads();
    {   // shared L1 (VALU): neuron t&255, 8 elems each
        const int n = t & 255;
        float w[22];
        #pragma unroll
        for (int k = 0; k < 22; ++k) w[k] = sw1[n * 22 + k];
        const float bias = sb1[n];
        #pragma unroll
        for (int ii = 0; ii < 8; ++ii) {
            int e = (t >> 8) * 8 + ii;
            float a = bias;
            #pragma unroll
            for (int k = 0; k < 22; ++k) a += w[k] * xs[e][k];
            h1s[e * 264 + n] = f2u(fmaxf(a, 0.f));
        }
    }
    __syncthreads();
    const int wv = t >> 6, lane = t & 63, quad = lane >> 4, l16 = lane & 15;
    {   // shared L2 (MFMA): M=16, wave N=32, K=256 -> seL
        f32x4 acc[2];
        #pragma unroll
        for (int nt = 0; nt < 2; ++nt) {
            float bv = sb2[wv * 32 + nt * 16 + l16];
            acc[nt] = {bv, bv, bv, bv};
        }
        const uint16_t* bb = sw2b + (size_t)(wv * 32 + l16) * 256 + quad * 8;
        bf16x8 bc[2], bn[2];
        bc[0] = *reinterpret_cast<const bf16x8*>(bb);
        bc[1] = *reinterpret_cast<const bf16x8*>(bb + 4096);
        #pragma unroll
        for (int kk = 0; kk < 8; ++kk) {
            if (kk < 7) {
                bn[0] = *reinterpret_cast<const bf16x8*>(bb + (kk + 1) * 32);
                bn[1] = *reinterpret_cast<const bf16x8*>(bb + 4096 + (kk + 1) * 32);
            }
            bf16x8 af = *reinterpret_cast<const bf16x8*>(
                &h1s[l16 * 264 + kk * 32 + quad * 8]);
            #pragma unroll
            for (int nt = 0; nt < 2; ++nt)
                acc[nt] = __builtin_amdgcn_mfma_f32_16x16x32_bf16(
                    af, bc[nt], acc[nt], 0, 0, 0);
            bc[0] = bn[0]; bc[1] = bn[1];
        }
        #pragma unroll
        for (int nt = 0; nt < 2; ++nt)
            #pragma unroll
            for (int r = 0; r < 4; ++r)
                seL[(quad * 4 + r) * 264 + wv * 32 + nt * 16 + l16] =
                    f2u(fmaxf(acc[nt][r], 0.f));
    }
    __syncthreads();
    {   // cse (MFMA): M=16, wave N=64, K=256, no relu -> ws
        f32x4 acc[4];
        #pragma unroll
        for (int nt = 0; nt < 4; ++nt) {
            float bv = tb1[wv * 64 + nt * 16 + l16];
            acc[nt] = {bv, bv, bv, bv};
        }
        const uint16_t* bb = tw1seb + (size_t)(wv * 64 + l16) * 256 + quad * 8;
        bf16x8 bc[4], bn[4];
        #pragma unroll
        for (int nt = 0; nt < 4; ++nt)
            bc[nt] = *reinterpret_cast<const bf16x8*>(bb + nt * 4096);
        #pragma unroll
        for (int kk = 0; kk < 8; ++kk) {
            if (kk < 7) {
                #pragma unroll
                for (int nt = 0; nt < 4; ++nt)
                    bn[nt] = *reinterpret_cast<const bf16x8*>(
                        bb + nt * 4096 + (kk + 1) * 32);
            }
            bf16x8 af = *reinterpret_cast<const bf16x8*>(
                &seL[l16 * 264 + kk * 32 + quad * 8]);
            #pragma unroll
            for (int nt = 0; nt < 4; ++nt)
                acc[nt] = __builtin_amdgcn_mfma_f32_16x16x32_bf16(
                    af, bc[nt], acc[nt], 0, 0, 0);
            #pragma unroll
            for (int nt = 0; nt < 4; ++nt) bc[nt] = bn[nt];
        }
        #pragma unroll
        for (int nt = 0; nt < 4; ++nt)
            #pragma unroll
            for (int r = 0; r < 4; ++r)
                ws[WCSE + (size_t)(b0 + quad * 4 + r) * 512 +
                   wv * 64 + nt * 16 + l16] = f2u(acc[nt][r]);
    }
}

// ---------------- k_main (R12 layout, swapped-operand MFMAs) ---------------
// LDS (bytes): uqb bf16[64][40] 0..5120 | noop f32[64] @5120 | cse bf16[4][512]
// @5376 | h1u bf16[64][136] @9472 | uet @26880 | h1t bf16[64][264] @44288
// (t2 overlays) -> 78080 B, 2 blocks/CU.
static constexpr int UQB_OFF  = 0;
static constexpr int NOOP_OFF = 5120;
static constexpr int CSE_OFF  = 5376;
static constexpr int H1U_OFF  = 9472;
static constexpr int UET_OFF  = 26880;
static constexpr int H1T_OFF  = 44288;
static constexpr int SMEM_SZ  = 78080;

__global__ __launch_bounds__(512, 4) void k_main(
    const float* __restrict__ obs,
    const float* __restrict__ ub1,
    const float* __restrict__ ub2, const float* __restrict__ emb,
    const float* __restrict__ tb2,
    const float* __restrict__ vw,  const float* __restrict__ vb,
    const float* __restrict__ dw,  const float* __restrict__ db,
    const uint16_t* __restrict__ wsb,
    float* __restrict__ out)
{
    __shared__ __align__(16) char smem[SMEM_SZ];
    uint16_t* uqb   = (uint16_t*)(smem + UQB_OFF);
    float*    noopf = (float*)(smem + NOOP_OFF);
    uint16_t* cseL  = (uint16_t*)(smem + CSE_OFF);
    uint16_t* h1u   = (uint16_t*)(smem + H1U_OFF);
    uint16_t* uet   = (uint16_t*)(smem + UET_OFF);
    uint16_t* h1t   = (uint16_t*)(smem + H1T_OFF);
    uint16_t* t2    = h1t;

    const int t    = threadIdx.x;
    const int wv   = t >> 6;
    const int lane = t & 63;
    const int quad = lane >> 4;
    const int l16  = lane & 15;
    const int b0   = blockIdx.x * 4;

    const uint16_t* csep  = wsb + WCSE;
    const uint16_t* tw1ue = wsb + WTW1UE;
    const uint16_t* tw2b  = wsb + WTW2;
    const uint16_t* uw2b  = wsb + WUW2;
    const uint16_t* uw1b  = wsb + WUW1B;

    // ---- stage 1: uqb bf16 [64][40] (K=32 zero-padded), noop, cse rows ----
    {
        int r = t >> 3, q = t & 7;               // row 0..63, k-quad 0..7
        int e = r >> 4, o = r & 15;
        ushort4 ov = {0, 0, 0, 0};
        if (q < 2) {                             // cols 0..7 real (8B-aligned)
            const float2* sp = reinterpret_cast<const float2*>(
                &obs[(size_t)(b0 + e) * 150 + 22 + o * 8 + q * 4]);
            float2 a = sp[0], b = sp[1];
            ov.x = f2u(a.x); ov.y = f2u(a.y); ov.z = f2u(b.x); ov.w = f2u(b.y);
        }
        *reinterpret_cast<ushort4*>(&uqb[r * 40 + q * 4]) = ov;
        #pragma unroll
        for (int ii = 0; ii < 2; ++ii) {         // cse rows: 1024 dwords
            int i = t + ii * 512;
            int ee = i >> 8, cc = i & 255;
            ((uint32_t*)cseL)[ee * 256 + cc] =
                ((const uint32_t*)(csep + (size_t)(b0 + ee) * 512))[cc];
        }
        if (t < 64) {
            int ee = t >> 4, oo = t & 15;
            noopf[t] = (obs[(size_t)(b0 + ee) * 150 + 22 + oo * 8] == 1.0f) ? 1.0f : 0.0f;
        }
    }
    __syncthreads();

    // ---- stage 2: unique L1, swapped mfma(W,X) -> lane holds 4 consecutive
    // neurons (wv*16+quad*4+r) for batch row mt*16+l16 -> b64 stores ----
    {
        float4 bv4 = *reinterpret_cast<const float4*>(&ub1[wv * 16 + quad * 4]);
        f32x4 acc[4];
        #pragma unroll
        for (int mt = 0; mt < 4; ++mt) acc[mt] = {bv4.x, bv4.y, bv4.z, bv4.w};
        bf16x8 wf = *reinterpret_cast<const bf16x8*>(
            &uw1b[(wv * 16 + l16) * 32 + quad * 8]);
        #pragma unroll
        for (int mt = 0; mt < 4; ++mt) {
            bf16x8 xf = *reinterpret_cast<const bf16x8*>(
                &uqb[(mt * 16 + l16) * 40 + quad * 8]);
            acc[mt] = __builtin_amdgcn_mfma_f32_16x16x32_bf16(wf, xf, acc[mt], 0, 0, 0);
        }
        #pragma unroll
        for (int mt = 0; mt < 4; ++mt) {
            ushort4 o = pack4(fmaxf(acc[mt][0], 0.f), fmaxf(acc[mt][1], 0.f),
                              fmaxf(acc[mt][2], 0.f), fmaxf(acc[mt][3], 0.f));
            *reinterpret_cast<ushort4*>(
                &h1u[(mt * 16 + l16) * 136 + wv * 16 + quad * 4]) = o;
        }
    }
    __syncthreads();

    // ---- stage 3: unique L2, swapped, K=128 -> uet (b64 stores) ----
    {
        float4 bv4 = *reinterpret_cast<const float4*>(&ub2[wv * 16 + quad * 4]);
        float4 ev4 = *reinterpret_cast<const float4*>(&emb[wv * 16 + quad * 4]);
        f32x4 acc[4];
        #pragma unroll
        for (int mt = 0; mt < 4; ++mt) acc[mt] = {bv4.x, bv4.y, bv4.z, bv4.w};
        #pragma unroll
        for (int kk = 0; kk < 4; ++kk) {
            bf16x8 wf = *reinterpret_cast<const bf16x8*>(
                &uw2b[(size_t)(wv * 16 + l16) * 128 + kk * 32 + quad * 8]);
            #pragma unroll
            for (int mt = 0; mt < 4; ++mt) {
                bf16x8 xf = *reinterpret_cast<const bf16x8*>(
                    &h1u[(mt * 16 + l16) * 136 + kk * 32 + quad * 8]);
                acc[mt] = __builtin_amdgcn_mfma_f32_16x16x32_bf16(wf, xf, acc[mt], 0, 0, 0);
            }
        }
        #pragma unroll
        for (int mt = 0; mt < 4; ++mt) {
            bool noop = (noopf[mt * 16 + l16] != 0.0f);
            ushort4 o = pack4(noop ? ev4.x : fmaxf(acc[mt][0], 0.f),
                              noop ? ev4.y : fmaxf(acc[mt][1], 0.f),
                              noop ? ev4.z : fmaxf(acc[mt][2], 0.f),
                              noop ? ev4.w : fmaxf(acc[mt][3], 0.f));
            *reinterpret_cast<ushort4*>(
                &uet[(mt * 16 + l16) * 136 + wv * 16 + quad * 4]) = o;
        }
    }
    __syncthreads();

    // ---- trunk: 2 N-chunks of 256; swapped L1 (acc init = cse) -> L2 ----
    f32x4 acc2[4][2];
    #pragma unroll
    for (int nt = 0; nt < 2; ++nt) {
        float4 bv4 = *reinterpret_cast<const float4*>(
            &tb2[wv * 32 + nt * 16 + quad * 4]);
        #pragma unroll
        for (int mt = 0; mt < 4; ++mt) acc2[mt][nt] = {bv4.x, bv4.y, bv4.z, bv4.w};
    }

    #pragma unroll
    for (int nc = 0; nc < 2; ++nc) {
        {
            f32x4 acc1[4][2];
            #pragma unroll
            for (int nt = 0; nt < 2; ++nt) {
                int n0 = nc * 256 + wv * 32 + nt * 16 + quad * 4;
                #pragma unroll
                for (int mt = 0; mt < 4; ++mt) {
                    ushort4 cv = *reinterpret_cast<const ushort4*>(
                        &cseL[mt * 512 + n0]);
                    acc1[mt][nt] = {u2f(cv.x), u2f(cv.y), u2f(cv.z), u2f(cv.w)};
                }
            }
            const uint16_t* bb = tw1ue + (size_t)(nc * 256 + wv * 32 + l16) * 128
                                 + quad * 8;
            bf16x8 bc[2], bn[2];
            bc[0] = *reinterpret_cast<const bf16x8*>(bb);
            bc[1] = *reinterpret_cast<const bf16x8*>(bb + 2048);
            #pragma unroll
            for (int kk = 0; kk < 4; ++kk) {
                if (kk < 3) {
                    bn[0] = *reinterpret_cast<const bf16x8*>(bb + (kk + 1) * 32);
                    bn[1] = *reinterpret_cast<const bf16x8*>(bb + 2048 + (kk + 1) * 32);
                }
                bf16x8 af[4];
                #pragma unroll
                for (int mt = 0; mt < 4; ++mt)
                    af[mt] = *reinterpret_cast<const bf16x8*>(
                        &uet[(mt * 16 + l16) * 136 + kk * 32 + quad * 8]);
                #pragma unroll
                for (int mt = 0; mt < 4; ++mt)
                    #pragma unroll
                    for (int nt = 0; nt < 2; ++nt)
                        acc1[mt][nt] = __builtin_amdgcn_mfma_f32_16x16x32_bf16(
                            bc[nt], af[mt], acc1[mt][nt], 0, 0, 0);
                bc[0] = bn[0]; bc[1] = bn[1];
            }
            #pragma unroll
            for (int mt = 0; mt < 4; ++mt)
                #pragma unroll
                for (int nt = 0; nt < 2; ++nt) {
                    ushort4 o = pack4(fmaxf(acc1[mt][nt][0], 0.f),
                                      fmaxf(acc1[mt][nt][1], 0.f),
                                      fmaxf(acc1[mt][nt][2], 0.f),
                                      fmaxf(acc1[mt][nt][3], 0.f));
                    *reinterpret_cast<ushort4*>(
                        &h1t[(mt * 16 + l16) * 264 + wv * 32 + nt * 16 + quad * 4]) = o;
                }
        }
        __syncthreads();
        {
            const uint16_t* cb = tw2b + (size_t)(wv * 32 + l16) * 512 + nc * 256
                                 + quad * 8;
            bf16x8 cc[2], cn[2];
            cc[0] = *reinterpret_cast<const bf16x8*>(cb);
            cc[1] = *reinterpret_cast<const bf16x8*>(cb + 8192);
            #pragma unroll
            for (int k2 = 0; k2 < 8; ++k2) {
                if (k2 < 7) {
                    cn[0] = *reinterpret_cast<const bf16x8*>(cb + (k2 + 1) * 32);
                    cn[1] = *reinterpret_cast<const bf16x8*>(cb + 8192 + (k2 + 1) * 32);
                }
                bf16x8 af[4];
                #pragma unroll
                for (int mt = 0; mt < 4; ++mt)
                    af[mt] = *reinterpret_cast<const bf16x8*>(
                        &h1t[(mt * 16 + l16) * 264 + k2 * 32 + quad * 8]);
                #pragma unroll
                for (int mt = 0; mt < 4; ++mt)
                    #pragma unroll
                    for (int nt = 0; nt < 2; ++nt)
                        acc2[mt][nt] = __builtin_amdgcn_mfma_f32_16x16x32_bf16(
                            cc[nt], af[mt], acc2[mt][nt], 0, 0, 0);
                cc[0] = cn[0]; cc[1] = cn[1];
            }
        }
        if (nc == 0) __syncthreads();
    }
    __syncthreads();
    #pragma unroll
    for (int mt = 0; mt < 4; ++mt)
        #pragma unroll
        for (int nt = 0; nt < 2; ++nt) {
            ushort4 o = pack4(fmaxf(acc2[mt][nt][0], 0.f),
                              fmaxf(acc2[mt][nt][1], 0.f),
                              fmaxf(acc2[mt][nt][2], 0.f),
                              fmaxf(acc2[mt][nt][3], 0.f));
            *reinterpret_cast<ushort4*>(
                &t2[(mt * 16 + l16) * 264 + wv * 32 + nt * 16 + quad * 4]) = o;
        }
    __syncthreads();

    // ---- heads ----
    {
        float vwf[4], dwf[4];
        #pragma unroll
        for (int j = 0; j < 4; ++j) {
            vwf[j] = vw[lane + 64 * j];
            dwf[j] = dw[lane + 64 * j];
        }
        const float vbf = vb[0], dbf = db[0];
        #pragma unroll
        for (int rr = 0; rr < 8; ++rr) {
            int row = wv * 8 + rr;
            float sv = 0.f, sd = 0.f;
            #pragma unroll
            for (int j = 0; j < 4; ++j) {
                float tv = u2f(t2[row * 264 + lane + 64 * j]);
                sv += tv * vwf[j];
                sd += tv * dwf[j];
            }
            #pragma unroll
            for (int off = 32; off > 0; off >>= 1) {
                sv += __shfl_down(sv, off);
                sd += __shfl_down(sd, off);
            }
            if (lane == 0) {
                int g = blockIdx.x * 64 + row;
                out[g] = sv + vbf;
                float z = sd + dbf;
                float sig = 1.f / (1.f + __expf(-z));
                out[B_ * 16 + g] = sig * 0.4f + 0.1f;
            }
        }
    }
}

extern "C" void kernel_launch(void* const* d_in, const int* in_sizes, int n_in,
                              void* d_out, int out_size, void* d_ws, size_t ws_size,
                              hipStream_t stream) {
    const float* obs = (const float*)d_in[0];
    const float* sw1 = (const float*)d_in[1];
    const float* sb1 = (const float*)d_in[2];
    const float* sw2 = (const float*)d_in[3];
    const float* sb2 = (const float*)d_in[4];
    const float* uw1 = (const float*)d_in[5];
    const float* ub1 = (const float*)d_in[6];
    const float* uw2 = (const float*)d_in[7];
    const float* ub2 = (const float*)d_in[8];
    const float* emb = (const float*)d_in[9];
    const float* tw1 = (const float*)d_in[10];
    const float* tb1 = (const float*)d_in[11];
    const float* tw2 = (const float*)d_in[12];
    const float* tb2 = (const float*)d_in[13];
    const float* vw  = (const float*)d_in[14];
    const float* vb  = (const float*)d_in[15];
    const float* dw  = (const float*)d_in[16];
    const float* db  = (const float*)d_in[17];

    uint16_t* wsb = (uint16_t*)d_ws;

    k_conv<<<404, 256, 0, stream>>>(tw1, tw2, uw2, sw2, uw1, wsb);
    k_cse<<<512, 512, 0, stream>>>(obs, sw1, sb1, sb2, tb1, wsb);
    k_main<<<B_ / 4, 512, 0, stream>>>(obs, ub1, ub2, emb, tb2,
                                       vw, vb, dw, db, wsb, (float*)d_out);
}

// Round 8
// 224.391 us; speedup vs baseline: 1.1363x; 1.0439x over previous
//
#include <hip/hip_runtime.h>
#include <stdint.h>

// GaitnetActor B=8192, OPT=16. Round 25: R24 base (swapped-operand MFMAs,
// 234.2us total, k_main 131.1). Two critical-path cuts:
// (1) in-register heads: use acc2 directly (lane owns rows mt*16+l16 x cols
//     wv*32+nt*16+quad*4+r) -> 64 FMA partials + shfl_xor(16,32) quad-reduce
//     + 4KB LDS wave-reduce; removes t2 32KB round-trip + 96-op shfl chains
//     + bf16 rounding of t (more accurate).
// (2) defer cse ds_write: stage1 issues the 2 dword global loads to regs;
//     ds_write happens after stage3 (covered by existing barrier) so the
//     HBM miss latency hides under stages 2-3.
// out[0:131072]=logits fp32, [131072:262144]=duration fp32.

static constexpr int B_ = 8192;

typedef __attribute__((ext_vector_type(8))) short bf16x8;
typedef __attribute__((ext_vector_type(4))) float f32x4;

__device__ __forceinline__ float u2f(uint16_t u) {
    union { uint32_t i; float f; } c; c.i = (uint32_t)u << 16; return c.f;
}
__device__ __forceinline__ uint16_t f2u(float f) {
    __bf16 b = (__bf16)f;                       // native RNE cvt on gfx950
    return __builtin_bit_cast(uint16_t, b);
}
__device__ __forceinline__ ushort4 pack4(float a, float b, float c, float d) {
    ushort4 o;
    o.x = f2u(a); o.y = f2u(b); o.z = f2u(c); o.w = f2u(d);
    return o;
}

// ws layout (uint16 elems)
static constexpr size_t WCSE   = 0;                    // bf16 [8192][512]
static constexpr size_t WTW1SE = 4194304;              // bf16 [512][256]
static constexpr size_t WTW1UE = WTW1SE + 131072;      // bf16 [512][128]
static constexpr size_t WTW2   = WTW1UE + 65536;       // bf16 [256][512]
static constexpr size_t WUW2   = WTW2 + 131072;        // bf16 [128][128]
static constexpr size_t WSW2   = WUW2 + 16384;         // bf16 [256][256]
static constexpr size_t WUW1B  = WSW2 + 65536;         // bf16 [128][32] 0-pad

// ---------------- k_conv: all weights fp32 -> bf16 (404 blocks) ------------
__global__ __launch_bounds__(256) void k_conv(
    const float* __restrict__ tw1, const float* __restrict__ tw2,
    const float* __restrict__ uw2, const float* __restrict__ sw2,
    const float* __restrict__ uw1, uint16_t* __restrict__ ws)
{
    int i4 = blockIdx.x * 256 + threadIdx.x;
    if (i4 >= 102400) {                          // uw1b: zero-padded K=32
        int q = i4 - 102400;                     // [0,1024)
        int n = q >> 3, k0 = (q & 7) * 4;
        ushort4 o = {0, 0, 0, 0};
        if (k0 < 8) {
            float4 v = *reinterpret_cast<const float4*>(uw1 + n * 8 + k0);
            o.x = f2u(v.x); o.y = f2u(v.y); o.z = f2u(v.z); o.w = f2u(v.w);
        }
        *reinterpret_cast<ushort4*>(ws + WUW1B + n * 32 + k0) = o;
        return;
    }
    const float* src; size_t dst;
    if (i4 < 32768) {                            // tw1 se-part (k<256)
        int g = i4 * 4, n = g >> 8, k = g & 255;
        src = tw1 + (size_t)n * 384 + k;
        dst = WTW1SE + (size_t)g;
    } else if (i4 < 49152) {                     // tw1 ue-part (k>=256)
        int q = i4 - 32768, n = q >> 5, w = q & 31;
        src = tw1 + (size_t)n * 384 + 256 + w * 4;
        dst = WTW1UE + (size_t)n * 128 + w * 4;
    } else if (i4 < 81920) {
        int q = (i4 - 49152) * 4;
        src = tw2 + q; dst = WTW2 + q;
    } else if (i4 < 86016) {
        int q = (i4 - 81920) * 4;
        src = uw2 + q; dst = WUW2 + q;
    } else {
        int q = (i4 - 86016) * 4;
        src = sw2 + q; dst = WSW2 + q;
    }
    float4 v = *reinterpret_cast<const float4*>(src);
    ushort4 o;
    o.x = f2u(v.x); o.y = f2u(v.y); o.z = f2u(v.z); o.w = f2u(v.w);
    *reinterpret_cast<ushort4*>(ws + dst) = o;
}

// ---------------- k_cse: se + cse, 16 elems/block, 512 thr (512 blocks) ----
__global__ __launch_bounds__(512) void k_cse(
    const float* __restrict__ obs,
    const float* __restrict__ sw1, const float* __restrict__ sb1,
    const float* __restrict__ sb2, const float* __restrict__ tb1,
    uint16_t* __restrict__ ws)
{
    __shared__ float xs[16][24];
    __shared__ uint16_t h1s[16 * 264];
    __shared__ uint16_t seL[16 * 264];
    const int t = threadIdx.x;
    const int b0 = blockIdx.x * 16;
    const uint16_t* sw2b   = ws + WSW2;
    const uint16_t* tw1seb = ws + WTW1SE;

    if (t < 352) {
        int e = t / 22, c = t - e * 22;
        xs[e][c] = obs[(size_t)(b0 + e) * 150 + c];
    }
    __syncthreads();
    {   // shared L1 (VALU): neuron t&255, 8 elems each
        const int n = t & 255;
        float w[22];
        #pragma unroll
        for (int k = 0; k < 22; ++k) w[k] = sw1[n * 22 + k];
        const float bias = sb1[n];
        #pragma unroll
        for (int ii = 0; ii < 8; ++ii) {
            int e = (t >> 8) * 8 + ii;
            float a = bias;
            #pragma unroll
            for (int k = 0; k < 22; ++k) a += w[k] * xs[e][k];
            h1s[e * 264 + n] = f2u(fmaxf(a, 0.f));
        }
    }
    __syncthreads();
    const int wv = t >> 6, lane = t & 63, quad = lane >> 4, l16 = lane & 15;
    {   // shared L2 (MFMA): M=16, wave N=32, K=256 -> seL
        f32x4 acc[2];
        #pragma unroll
        for (int nt = 0; nt < 2; ++nt) {
            float bv = sb2[wv * 32 + nt * 16 + l16];
            acc[nt] = {bv, bv, bv, bv};
        }
        const uint16_t* bb = sw2b + (size_t)(wv * 32 + l16) * 256 + quad * 8;
        bf16x8 bc[2], bn[2];
        bc[0] = *reinterpret_cast<const bf16x8*>(bb);
        bc[1] = *reinterpret_cast<const bf16x8*>(bb + 4096);
        #pragma unroll
        for (int kk = 0; kk < 8; ++kk) {
            if (kk < 7) {
                bn[0] = *reinterpret_cast<const bf16x8*>(bb + (kk + 1) * 32);
                bn[1] = *reinterpret_cast<const bf16x8*>(bb + 4096 + (kk + 1) * 32);
            }
            bf16x8 af = *reinterpret_cast<const bf16x8*>(
                &h1s[l16 * 264 + kk * 32 + quad * 8]);
            #pragma unroll
            for (int nt = 0; nt < 2; ++nt)
                acc[nt] = __builtin_amdgcn_mfma_f32_16x16x32_bf16(
                    af, bc[nt], acc[nt], 0, 0, 0);
            bc[0] = bn[0]; bc[1] = bn[1];
        }
        #pragma unroll
        for (int nt = 0; nt < 2; ++nt)
            #pragma unroll
            for (int r = 0; r < 4; ++r)
                seL[(quad * 4 + r) * 264 + wv * 32 + nt * 16 + l16] =
                    f2u(fmaxf(acc[nt][r], 0.f));
    }
    __syncthreads();
    {   // cse (MFMA): M=16, wave N=64, K=256, no relu -> ws
        f32x4 acc[4];
        #pragma unroll
        for (int nt = 0; nt < 4; ++nt) {
            float bv = tb1[wv * 64 + nt * 16 + l16];
            acc[nt] = {bv, bv, bv, bv};
        }
        const uint16_t* bb = tw1seb + (size_t)(wv * 64 + l16) * 256 + quad * 8;
        bf16x8 bc[4], bn[4];
        #pragma unroll
        for (int nt = 0; nt < 4; ++nt)
            bc[nt] = *reinterpret_cast<const bf16x8*>(bb + nt * 4096);
        #pragma unroll
        for (int kk = 0; kk < 8; ++kk) {
            if (kk < 7) {
                #pragma unroll
                for (int nt = 0; nt < 4; ++nt)
                    bn[nt] = *reinterpret_cast<const bf16x8*>(
                        bb + nt * 4096 + (kk + 1) * 32);
            }
            bf16x8 af = *reinterpret_cast<const bf16x8*>(
                &seL[l16 * 264 + kk * 32 + quad * 8]);
            #pragma unroll
            for (int nt = 0; nt < 4; ++nt)
                acc[nt] = __builtin_amdgcn_mfma_f32_16x16x32_bf16(
                    af, bc[nt], acc[nt], 0, 0, 0);
            #pragma unroll
            for (int nt = 0; nt < 4; ++nt) bc[nt] = bn[nt];
        }
        #pragma unroll
        for (int nt = 0; nt < 4; ++nt)
            #pragma unroll
            for (int r = 0; r < 4; ++r)
                ws[WCSE + (size_t)(b0 + quad * 4 + r) * 512 +
                   wv * 64 + nt * 16 + l16] = f2u(acc[nt][r]);
    }
}

// ---------------- k_main (swapped MFMAs, in-reg heads, deferred cse) -------
// LDS (bytes): uqb bf16[64][40] 0..5120 | noop f32[64] @5120 | cse bf16[4][512]
// @5376 | h1u bf16[64][136] @9472 | uet @26880 | h1t bf16[64][264] @44288
// (hred f32[1024] overlays h1t after trunk) -> 78080 B, 2 blocks/CU.
static constexpr int UQB_OFF  = 0;
static constexpr int NOOP_OFF = 5120;
static constexpr int CSE_OFF  = 5376;
static constexpr int H1U_OFF  = 9472;
static constexpr int UET_OFF  = 26880;
static constexpr int H1T_OFF  = 44288;
static constexpr int SMEM_SZ  = 78080;

__global__ __launch_bounds__(512, 4) void k_main(
    const float* __restrict__ obs,
    const float* __restrict__ ub1,
    const float* __restrict__ ub2, const float* __restrict__ emb,
    const float* __restrict__ tb2,
    const float* __restrict__ vw,  const float* __restrict__ vb,
    const float* __restrict__ dw,  const float* __restrict__ db,
    const uint16_t* __restrict__ wsb,
    float* __restrict__ out)
{
    __shared__ __align__(16) char smem[SMEM_SZ];
    uint16_t* uqb   = (uint16_t*)(smem + UQB_OFF);
    float*    noopf = (float*)(smem + NOOP_OFF);
    uint16_t* cseL  = (uint16_t*)(smem + CSE_OFF);
    uint16_t* h1u   = (uint16_t*)(smem + H1U_OFF);
    uint16_t* uet   = (uint16_t*)(smem + UET_OFF);
    uint16_t* h1t   = (uint16_t*)(smem + H1T_OFF);
    float*    hred  = (float*)(smem + H1T_OFF);

    const int t    = threadIdx.x;
    const int wv   = t >> 6;
    const int lane = t & 63;
    const int quad = lane >> 4;
    const int l16  = lane & 15;
    const int b0   = blockIdx.x * 4;

    const uint16_t* csep  = wsb + WCSE;
    const uint16_t* tw1ue = wsb + WTW1UE;
    const uint16_t* tw2b  = wsb + WTW2;
    const uint16_t* uw2b  = wsb + WUW2;
    const uint16_t* uw1b  = wsb + WUW1B;

    // ---- stage 1: uqb bf16 [64][40] (K=32 zero-padded), noop; cse -> regs --
    uint32_t cse_r0, cse_r1;
    {
        int r = t >> 3, q = t & 7;               // row 0..63, k-quad 0..7
        int e = r >> 4, o = r & 15;
        ushort4 ov = {0, 0, 0, 0};
        if (q < 2) {                             // cols 0..7 real (8B-aligned)
            const float2* sp = reinterpret_cast<const float2*>(
                &obs[(size_t)(b0 + e) * 150 + 22 + o * 8 + q * 4]);
            float2 a = sp[0], b = sp[1];
            ov.x = f2u(a.x); ov.y = f2u(a.y); ov.z = f2u(b.x); ov.w = f2u(b.y);
        }
        *reinterpret_cast<ushort4*>(&uqb[r * 40 + q * 4]) = ov;
        const uint32_t* cp = (const uint32_t*)(csep + (size_t)b0 * 512);
        cse_r0 = cp[t];
        cse_r1 = cp[t + 512];
        if (t < 64) {
            int ee = t >> 4, oo = t & 15;
            noopf[t] = (obs[(size_t)(b0 + ee) * 150 + 22 + oo * 8] == 1.0f) ? 1.0f : 0.0f;
        }
    }
    __syncthreads();

    // ---- stage 2: unique L1, swapped mfma(W,X) -> b64 stores ----
    {
        float4 bv4 = *reinterpret_cast<const float4*>(&ub1[wv * 16 + quad * 4]);
        f32x4 acc[4];
        #pragma unroll
        for (int mt = 0; mt < 4; ++mt) acc[mt] = {bv4.x, bv4.y, bv4.z, bv4.w};
        bf16x8 wf = *reinterpret_cast<const bf16x8*>(
            &uw1b[(wv * 16 + l16) * 32 + quad * 8]);
        #pragma unroll
        for (int mt = 0; mt < 4; ++mt) {
            bf16x8 xf = *reinterpret_cast<const bf16x8*>(
                &uqb[(mt * 16 + l16) * 40 + quad * 8]);
            acc[mt] = __builtin_amdgcn_mfma_f32_16x16x32_bf16(wf, xf, acc[mt], 0, 0, 0);
        }
        #pragma unroll
        for (int mt = 0; mt < 4; ++mt) {
            ushort4 o = pack4(fmaxf(acc[mt][0], 0.f), fmaxf(acc[mt][1], 0.f),
                              fmaxf(acc[mt][2], 0.f), fmaxf(acc[mt][3], 0.f));
            *reinterpret_cast<ushort4*>(
                &h1u[(mt * 16 + l16) * 136 + wv * 16 + quad * 4]) = o;
        }
    }
    __syncthreads();

    // ---- stage 3: unique L2, swapped, K=128 -> uet (b64 stores) ----
    {
        float4 bv4 = *reinterpret_cast<const float4*>(&ub2[wv * 16 + quad * 4]);
        float4 ev4 = *reinterpret_cast<const float4*>(&emb[wv * 16 + quad * 4]);
        f32x4 acc[4];
        #pragma unroll
        for (int mt = 0; mt < 4; ++mt) acc[mt] = {bv4.x, bv4.y, bv4.z, bv4.w};
        #pragma unroll
        for (int kk = 0; kk < 4; ++kk) {
            bf16x8 wf = *reinterpret_cast<const bf16x8*>(
                &uw2b[(size_t)(wv * 16 + l16) * 128 + kk * 32 + quad * 8]);
            #pragma unroll
            for (int mt = 0; mt < 4; ++mt) {
                bf16x8 xf = *reinterpret_cast<const bf16x8*>(
                    &h1u[(mt * 16 + l16) * 136 + kk * 32 + quad * 8]);
                acc[mt] = __builtin_amdgcn_mfma_f32_16x16x32_bf16(wf, xf, acc[mt], 0, 0, 0);
            }
        }
        #pragma unroll
        for (int mt = 0; mt < 4; ++mt) {
            bool noop = (noopf[mt * 16 + l16] != 0.0f);
            ushort4 o = pack4(noop ? ev4.x : fmaxf(acc[mt][0], 0.f),
                              noop ? ev4.y : fmaxf(acc[mt][1], 0.f),
                              noop ? ev4.z : fmaxf(acc[mt][2], 0.f),
                              noop ? ev4.w : fmaxf(acc[mt][3], 0.f));
            *reinterpret_cast<ushort4*>(
                &uet[(mt * 16 + l16) * 136 + wv * 16 + quad * 4]) = o;
        }
        // deferred cse LDS write (loads issued in stage 1, latency hidden)
        ((uint32_t*)cseL)[t] = cse_r0;
        ((uint32_t*)cseL)[t + 512] = cse_r1;
    }
    __syncthreads();

    // ---- trunk: 2 N-chunks of 256; swapped L1 (acc init = cse) -> L2 ----
    f32x4 acc2[4][2];
    #pragma unroll
    for (int nt = 0; nt < 2; ++nt) {
        float4 bv4 = *reinterpret_cast<const float4*>(
            &tb2[wv * 32 + nt * 16 + quad * 4]);
        #pragma unroll
        for (int mt = 0; mt < 4; ++mt) acc2[mt][nt] = {bv4.x, bv4.y, bv4.z, bv4.w};
    }

    #pragma unroll
    for (int nc = 0; nc < 2; ++nc) {
        {
            f32x4 acc1[4][2];
            #pragma unroll
            for (int nt = 0; nt < 2; ++nt) {
                int n0 = nc * 256 + wv * 32 + nt * 16 + quad * 4;
                #pragma unroll
                for (int mt = 0; mt < 4; ++mt) {
                    ushort4 cv = *reinterpret_cast<const ushort4*>(
                        &cseL[mt * 512 + n0]);
                    acc1[mt][nt] = {u2f(cv.x), u2f(cv.y), u2f(cv.z), u2f(cv.w)};
                }
            }
            const uint16_t* bb = tw1ue + (size_t)(nc * 256 + wv * 32 + l16) * 128
                                 + quad * 8;
            bf16x8 bc[2], bn[2];
            bc[0] = *reinterpret_cast<const bf16x8*>(bb);
            bc[1] = *reinterpret_cast<const bf16x8*>(bb + 2048);
            #pragma unroll
            for (int kk = 0; kk < 4; ++kk) {
                if (kk < 3) {
                    bn[0] = *reinterpret_cast<const bf16x8*>(bb + (kk + 1) * 32);
                    bn[1] = *reinterpret_cast<const bf16x8*>(bb + 2048 + (kk + 1) * 32);
                }
                bf16x8 af[4];
                #pragma unroll
                for (int mt = 0; mt < 4; ++mt)
                    af[mt] = *reinterpret_cast<const bf16x8*>(
                        &uet[(mt * 16 + l16) * 136 + kk * 32 + quad * 8]);
                #pragma unroll
                for (int mt = 0; mt < 4; ++mt)
                    #pragma unroll
                    for (int nt = 0; nt < 2; ++nt)
                        acc1[mt][nt] = __builtin_amdgcn_mfma_f32_16x16x32_bf16(
                            bc[nt], af[mt], acc1[mt][nt], 0, 0, 0);
                bc[0] = bn[0]; bc[1] = bn[1];
            }
            #pragma unroll
            for (int mt = 0; mt < 4; ++mt)
                #pragma unroll
                for (int nt = 0; nt < 2; ++nt) {
                    ushort4 o = pack4(fmaxf(acc1[mt][nt][0], 0.f),
                                      fmaxf(acc1[mt][nt][1], 0.f),
                                      fmaxf(acc1[mt][nt][2], 0.f),
                                      fmaxf(acc1[mt][nt][3], 0.f));
                    *reinterpret_cast<ushort4*>(
                        &h1t[(mt * 16 + l16) * 264 + wv * 32 + nt * 16 + quad * 4]) = o;
                }
        }
        __syncthreads();
        {
            const uint16_t* cb = tw2b + (size_t)(wv * 32 + l16) * 512 + nc * 256
                                 + quad * 8;
            bf16x8 cc[2], cn[2];
            cc[0] = *reinterpret_cast<const bf16x8*>(cb);
            cc[1] = *reinterpret_cast<const bf16x8*>(cb + 8192);
            #pragma unroll
            for (int k2 = 0; k2 < 8; ++k2) {
                if (k2 < 7) {
                    cn[0] = *reinterpret_cast<const bf16x8*>(cb + (k2 + 1) * 32);
                    cn[1] = *reinterpret_cast<const bf16x8*>(cb + 8192 + (k2 + 1) * 32);
                }
                bf16x8 af[4];
                #pragma unroll
                for (int mt = 0; mt < 4; ++mt)
                    af[mt] = *reinterpret_cast<const bf16x8*>(
                        &h1t[(mt * 16 + l16) * 264 + k2 * 32 + quad * 8]);
                #pragma unroll
                for (int mt = 0; mt < 4; ++mt)
                    #pragma unroll
                    for (int nt = 0; nt < 2; ++nt)
                        acc2[mt][nt] = __builtin_amdgcn_mfma_f32_16x16x32_bf16(
                            cc[nt], af[mt], acc2[mt][nt], 0, 0, 0);
                cc[0] = cn[0]; cc[1] = cn[1];
            }
        }
        if (nc == 0) __syncthreads();
    }
    __syncthreads();                             // last h1t read done

    // ---- heads: in-register from acc2 (fp32 t, no bf16 round) ----
    {
        float svr[4] = {0.f, 0.f, 0.f, 0.f};
        float sdr[4] = {0.f, 0.f, 0.f, 0.f};
        #pragma unroll
        for (int nt = 0; nt < 2; ++nt) {
            float4 vw4 = *reinterpret_cast<const float4*>(
                &vw[wv * 32 + nt * 16 + quad * 4]);
            float4 dw4 = *reinterpret_cast<const float4*>(
                &dw[wv * 32 + nt * 16 + quad * 4]);
            #pragma unroll
            for (int mt = 0; mt < 4; ++mt) {
                float t0 = fmaxf(acc2[mt][nt][0], 0.f);
                float t1 = fmaxf(acc2[mt][nt][1], 0.f);
                float t2 = fmaxf(acc2[mt][nt][2], 0.f);
                float t3 = fmaxf(acc2[mt][nt][3], 0.f);
                svr[mt] += t0 * vw4.x + t1 * vw4.y + t2 * vw4.z + t3 * vw4.w;
                sdr[mt] += t0 * dw4.x + t1 * dw4.y + t2 * dw4.z + t3 * dw4.w;
            }
        }
        #pragma unroll
        for (int mt = 0; mt < 4; ++mt) {         // reduce over quads
            svr[mt] += __shfl_xor(svr[mt], 16);
            svr[mt] += __shfl_xor(svr[mt], 32);
            sdr[mt] += __shfl_xor(sdr[mt], 16);
            sdr[mt] += __shfl_xor(sdr[mt], 32);
        }
        if (quad == 0) {                         // stage per-wave partials
            #pragma unroll
            for (int mt = 0; mt < 4; ++mt) {
                int row = mt * 16 + l16;
                hred[(row * 2 + 0) * 8 + wv] = svr[mt];
                hred[(row * 2 + 1) * 8 + wv] = sdr[mt];
            }
        }
    }
    __syncthreads();
    if (t < 128) {                               // final reduce over 8 waves
        const float* p = &hred[t * 8];
        float s = p[0] + p[1] + p[2] + p[3] + p[4] + p[5] + p[6] + p[7];
        int row = t >> 1;
        int g = blockIdx.x * 64 + row;
        if ((t & 1) == 0) {
            out[g] = s + vb[0];
        } else {
            float z = s + db[0];
            float sig = 1.f / (1.f + __expf(-z));
            out[B_ * 16 + g] = sig * 0.4f + 0.1f;
        }
    }
}

extern "C" void kernel_launch(void* const* d_in, const int* in_sizes, int n_in,
                              void* d_out, int out_size, void* d_ws, size_t ws_size,
                              hipStream_t stream) {
    const float* obs = (const float*)d_in[0];
    const float* sw1 = (const float*)d_in[1];
    const float* sb1 = (const float*)d_in[2];
    const float* sw2 = (const float*)d_in[3];
    const float* sb2 = (const float*)d_in[4];
    const float* uw1 = (const float*)d_in[5];
    const float* ub1 = (const float*)d_in[6];
    const float* uw2 = (const float*)d_in[7];
    const float* ub2 = (const float*)d_in[8];
    const float* emb = (const float*)d_in[9];
    const float* tw1 = (const float*)d_in[10];
    const float* tb1 = (const float*)d_in[11];
    const float* tw2 = (const float*)d_in[12];
    const float* tb2 = (const float*)d_in[13];
    const float* vw  = (const float*)d_in[14];
    const float* vb  = (const float*)d_in[15];
    const float* dw  = (const float*)d_in[16];
    const float* db  = (const float*)d_in[17];

    uint16_t* wsb = (uint16_t*)d_ws;

    k_conv<<<404, 256, 0, stream>>>(tw1, tw2, uw2, sw2, uw1, wsb);
    k_cse<<<512, 512, 0, stream>>>(obs, sw1, sb1, sb2, tb1, wsb);
    k_main<<<B_ / 4, 512, 0, stream>>>(obs, ub1, ub2, emb, tb2,
                                       vw, vb, dw, db, wsb, (float*)d_out);
}

// Round 9
// 222.404 us; speedup vs baseline: 1.1464x; 1.0089x over previous
//
#include <hip/hip_runtime.h>
#include <stdint.h>

// GaitnetActor B=8192, OPT=16. Round 26: R25 base (224.4us; swapped MFMAs,
// in-reg heads, deferred cse write). New: issue-early (T14) global B loads
// across every barrier in k_main and k_cse. __syncthreads is a full fence,
// so the compiler can't hoist phase-head L2 loads (~200-500cy) -- do it
// manually: trunk cc loads issued at L1-phase top, nc=1 bc during nc=0 L2
// phase, stage3 wf0 during stage2, stage2 wf during stage1, k_cse B pairs
// one phase early. No layout or numeric change (absmax identical).
// out[0:131072]=logits fp32, [131072:262144]=duration fp32.

static constexpr int B_ = 8192;

typedef __attribute__((ext_vector_type(8))) short bf16x8;
typedef __attribute__((ext_vector_type(4))) float f32x4;

__device__ __forceinline__ float u2f(uint16_t u) {
    union { uint32_t i; float f; } c; c.i = (uint32_t)u << 16; return c.f;
}
__device__ __forceinline__ uint16_t f2u(float f) {
    __bf16 b = (__bf16)f;                       // native RNE cvt on gfx950
    return __builtin_bit_cast(uint16_t, b);
}
__device__ __forceinline__ ushort4 pack4(float a, float b, float c, float d) {
    ushort4 o;
    o.x = f2u(a); o.y = f2u(b); o.z = f2u(c); o.w = f2u(d);
    return o;
}

// ws layout (uint16 elems)
static constexpr size_t WCSE   = 0;                    // bf16 [8192][512]
static constexpr size_t WTW1SE = 4194304;              // bf16 [512][256]
static constexpr size_t WTW1UE = WTW1SE + 131072;      // bf16 [512][128]
static constexpr size_t WTW2   = WTW1UE + 65536;       // bf16 [256][512]
static constexpr size_t WUW2   = WTW2 + 131072;        // bf16 [128][128]
static constexpr size_t WSW2   = WUW2 + 16384;         // bf16 [256][256]
static constexpr size_t WUW1B  = WSW2 + 65536;         // bf16 [128][32] 0-pad

// ---------------- k_conv: all weights fp32 -> bf16 (404 blocks) ------------
__global__ __launch_bounds__(256) void k_conv(
    const float* __restrict__ tw1, const float* __restrict__ tw2,
    const float* __restrict__ uw2, const float* __restrict__ sw2,
    const float* __restrict__ uw1, uint16_t* __restrict__ ws)
{
    int i4 = blockIdx.x * 256 + threadIdx.x;
    if (i4 >= 102400) {                          // uw1b: zero-padded K=32
        int q = i4 - 102400;                     // [0,1024)
        int n = q >> 3, k0 = (q & 7) * 4;
        ushort4 o = {0, 0, 0, 0};
        if (k0 < 8) {
            float4 v = *reinterpret_cast<const float4*>(uw1 + n * 8 + k0);
            o.x = f2u(v.x); o.y = f2u(v.y); o.z = f2u(v.z); o.w = f2u(v.w);
        }
        *reinterpret_cast<ushort4*>(ws + WUW1B + n * 32 + k0) = o;
        return;
    }
    const float* src; size_t dst;
    if (i4 < 32768) {                            // tw1 se-part (k<256)
        int g = i4 * 4, n = g >> 8, k = g & 255;
        src = tw1 + (size_t)n * 384 + k;
        dst = WTW1SE + (size_t)g;
    } else if (i4 < 49152) {                     // tw1 ue-part (k>=256)
        int q = i4 - 32768, n = q >> 5, w = q & 31;
        src = tw1 + (size_t)n * 384 + 256 + w * 4;
        dst = WTW1UE + (size_t)n * 128 + w * 4;
    } else if (i4 < 81920) {
        int q = (i4 - 49152) * 4;
        src = tw2 + q; dst = WTW2 + q;
    } else if (i4 < 86016) {
        int q = (i4 - 81920) * 4;
        src = uw2 + q; dst = WUW2 + q;
    } else {
        int q = (i4 - 86016) * 4;
        src = sw2 + q; dst = WSW2 + q;
    }
    float4 v = *reinterpret_cast<const float4*>(src);
    ushort4 o;
    o.x = f2u(v.x); o.y = f2u(v.y); o.z = f2u(v.z); o.w = f2u(v.w);
    *reinterpret_cast<ushort4*>(ws + dst) = o;
}

// ---------------- k_cse: se + cse, 16 elems/block, 512 thr (512 blocks) ----
__global__ __launch_bounds__(512) void k_cse(
    const float* __restrict__ obs,
    const float* __restrict__ sw1, const float* __restrict__ sb1,
    const float* __restrict__ sb2, const float* __restrict__ tb1,
    uint16_t* __restrict__ ws)
{
    __shared__ float xs[16][24];
    __shared__ uint16_t h1s[16 * 264];
    __shared__ uint16_t seL[16 * 264];
    const int t = threadIdx.x;
    const int b0 = blockIdx.x * 16;
    const int wv = t >> 6, lane = t & 63, quad = lane >> 4, l16 = lane & 15;
    const uint16_t* sw2b   = ws + WSW2;
    const uint16_t* tw1seb = ws + WTW1SE;

    if (t < 352) {
        int e = t / 22, c = t - e * 22;
        xs[e][c] = obs[(size_t)(b0 + e) * 150 + c];
    }
    __syncthreads();
    // issue-early: shared-L2 phase's first B pair (in flight through L1)
    const uint16_t* bb_se = sw2b + (size_t)(wv * 32 + l16) * 256 + quad * 8;
    bf16x8 seb0 = *reinterpret_cast<const bf16x8*>(bb_se);
    bf16x8 seb1 = *reinterpret_cast<const bf16x8*>(bb_se + 4096);
    {   // shared L1 (VALU): neuron t&255, 8 elems each
        const int n = t & 255;
        float w[22];
        #pragma unroll
        for (int k = 0; k < 22; ++k) w[k] = sw1[n * 22 + k];
        const float bias = sb1[n];
        #pragma unroll
        for (int ii = 0; ii < 8; ++ii) {
            int e = (t >> 8) * 8 + ii;
            float a = bias;
            #pragma unroll
            for (int k = 0; k < 22; ++k) a += w[k] * xs[e][k];
            h1s[e * 264 + n] = f2u(fmaxf(a, 0.f));
        }
    }
    __syncthreads();
    // issue-early: cse phase's first 4 B fragments (in flight through se-L2)
    const uint16_t* bb_c = tw1seb + (size_t)(wv * 64 + l16) * 256 + quad * 8;
    bf16x8 cseb[4];
    #pragma unroll
    for (int nt = 0; nt < 4; ++nt)
        cseb[nt] = *reinterpret_cast<const bf16x8*>(bb_c + nt * 4096);
    {   // shared L2 (MFMA): M=16, wave N=32, K=256 -> seL
        f32x4 acc[2];
        #pragma unroll
        for (int nt = 0; nt < 2; ++nt) {
            float bv = sb2[wv * 32 + nt * 16 + l16];
            acc[nt] = {bv, bv, bv, bv};
        }
        bf16x8 bc[2], bn[2];
        bc[0] = seb0; bc[1] = seb1;
        #pragma unroll
        for (int kk = 0; kk < 8; ++kk) {
            if (kk < 7) {
                bn[0] = *reinterpret_cast<const bf16x8*>(bb_se + (kk + 1) * 32);
                bn[1] = *reinterpret_cast<const bf16x8*>(bb_se + 4096 + (kk + 1) * 32);
            }
            bf16x8 af = *reinterpret_cast<const bf16x8*>(
                &h1s[l16 * 264 + kk * 32 + quad * 8]);
            #pragma unroll
            for (int nt = 0; nt < 2; ++nt)
                acc[nt] = __builtin_amdgcn_mfma_f32_16x16x32_bf16(
                    af, bc[nt], acc[nt], 0, 0, 0);
            bc[0] = bn[0]; bc[1] = bn[1];
        }
        #pragma unroll
        for (int nt = 0; nt < 2; ++nt)
            #pragma unroll
            for (int r = 0; r < 4; ++r)
                seL[(quad * 4 + r) * 264 + wv * 32 + nt * 16 + l16] =
                    f2u(fmaxf(acc[nt][r], 0.f));
    }
    __syncthreads();
    {   // cse (MFMA): M=16, wave N=64, K=256, no relu -> ws
        f32x4 acc[4];
        #pragma unroll
        for (int nt = 0; nt < 4; ++nt) {
            float bv = tb1[wv * 64 + nt * 16 + l16];
            acc[nt] = {bv, bv, bv, bv};
        }
        bf16x8 bc[4], bn[4];
        #pragma unroll
        for (int nt = 0; nt < 4; ++nt) bc[nt] = cseb[nt];
        #pragma unroll
        for (int kk = 0; kk < 8; ++kk) {
            if (kk < 7) {
                #pragma unroll
                for (int nt = 0; nt < 4; ++nt)
                    bn[nt] = *reinterpret_cast<const bf16x8*>(
                        bb_c + nt * 4096 + (kk + 1) * 32);
            }
            bf16x8 af = *reinterpret_cast<const bf16x8*>(
                &seL[l16 * 264 + kk * 32 + quad * 8]);
            #pragma unroll
            for (int nt = 0; nt < 4; ++nt)
                acc[nt] = __builtin_amdgcn_mfma_f32_16x16x32_bf16(
                    af, bc[nt], acc[nt], 0, 0, 0);
            #pragma unroll
            for (int nt = 0; nt < 4; ++nt) bc[nt] = bn[nt];
        }
        #pragma unroll
        for (int nt = 0; nt < 4; ++nt)
            #pragma unroll
            for (int r = 0; r < 4; ++r)
                ws[WCSE + (size_t)(b0 + quad * 4 + r) * 512 +
                   wv * 64 + nt * 16 + l16] = f2u(acc[nt][r]);
    }
}

// ---- k_main (swapped MFMAs, in-reg heads, deferred cse, issue-early) ------
// LDS (bytes): uqb bf16[64][40] 0..5120 | noop f32[64] @5120 | cse bf16[4][512]
// @5376 | h1u bf16[64][136] @9472 | uet @26880 | h1t bf16[64][264] @44288
// (hred f32[1024] overlays h1t after trunk) -> 78080 B, 2 blocks/CU.
static constexpr int UQB_OFF  = 0;
static constexpr int NOOP_OFF = 5120;
static constexpr int CSE_OFF  = 5376;
static constexpr int H1U_OFF  = 9472;
static constexpr int UET_OFF  = 26880;
static constexpr int H1T_OFF  = 44288;
static constexpr int SMEM_SZ  = 78080;

__global__ __launch_bounds__(512, 4) void k_main(
    const float* __restrict__ obs,
    const float* __restrict__ ub1,
    const float* __restrict__ ub2, const float* __restrict__ emb,
    const float* __restrict__ tb2,
    const float* __restrict__ vw,  const float* __restrict__ vb,
    const float* __restrict__ dw,  const float* __restrict__ db,
    const uint16_t* __restrict__ wsb,
    float* __restrict__ out)
{
    __shared__ __align__(16) char smem[SMEM_SZ];
    uint16_t* uqb   = (uint16_t*)(smem + UQB_OFF);
    float*    noopf = (float*)(smem + NOOP_OFF);
    uint16_t* cseL  = (uint16_t*)(smem + CSE_OFF);
    uint16_t* h1u   = (uint16_t*)(smem + H1U_OFF);
    uint16_t* uet   = (uint16_t*)(smem + UET_OFF);
    uint16_t* h1t   = (uint16_t*)(smem + H1T_OFF);
    float*    hred  = (float*)(smem + H1T_OFF);

    const int t    = threadIdx.x;
    const int wv   = t >> 6;
    const int lane = t & 63;
    const int quad = lane >> 4;
    const int l16  = lane & 15;
    const int b0   = blockIdx.x * 4;

    const uint16_t* csep  = wsb + WCSE;
    const uint16_t* tw1ue = wsb + WTW1UE;
    const uint16_t* tw2b  = wsb + WTW2;
    const uint16_t* uw2b  = wsb + WUW2;
    const uint16_t* uw1b  = wsb + WUW1B;

    // ---- stage 1: uqb bf16 [64][40] (K=32 zero-padded), noop; cse -> regs --
    uint32_t cse_r0, cse_r1;
    bf16x8 wf2;                                  // stage2 W (issue-early)
    {
        int r = t >> 3, q = t & 7;               // row 0..63, k-quad 0..7
        int e = r >> 4, o = r & 15;
        ushort4 ov = {0, 0, 0, 0};
        if (q < 2) {                             // cols 0..7 real (8B-aligned)
            const float2* sp = reinterpret_cast<const float2*>(
                &obs[(size_t)(b0 + e) * 150 + 22 + o * 8 + q * 4]);
            float2 a = sp[0], b = sp[1];
            ov.x = f2u(a.x); ov.y = f2u(a.y); ov.z = f2u(b.x); ov.w = f2u(b.y);
        }
        *reinterpret_cast<ushort4*>(&uqb[r * 40 + q * 4]) = ov;
        const uint32_t* cp = (const uint32_t*)(csep + (size_t)b0 * 512);
        cse_r0 = cp[t];
        cse_r1 = cp[t + 512];
        wf2 = *reinterpret_cast<const bf16x8*>(
            &uw1b[(wv * 16 + l16) * 32 + quad * 8]);
        if (t < 64) {
            int ee = t >> 4, oo = t & 15;
            noopf[t] = (obs[(size_t)(b0 + ee) * 150 + 22 + oo * 8] == 1.0f) ? 1.0f : 0.0f;
        }
    }
    __syncthreads();

    // ---- stage 2: unique L1, swapped mfma(W,X) -> b64 stores ----
    bf16x8 wf3;                                  // stage3 kk=0 W (issue-early)
    {
        float4 bv4 = *reinterpret_cast<const float4*>(&ub1[wv * 16 + quad * 4]);
        f32x4 acc[4];
        #pragma unroll
        for (int mt = 0; mt < 4; ++mt) acc[mt] = {bv4.x, bv4.y, bv4.z, bv4.w};
        #pragma unroll
        for (int mt = 0; mt < 4; ++mt) {
            bf16x8 xf = *reinterpret_cast<const bf16x8*>(
                &uqb[(mt * 16 + l16) * 40 + quad * 8]);
            acc[mt] = __builtin_amdgcn_mfma_f32_16x16x32_bf16(wf2, xf, acc[mt], 0, 0, 0);
        }
        wf3 = *reinterpret_cast<const bf16x8*>(
            &uw2b[(size_t)(wv * 16 + l16) * 128 + quad * 8]);
        #pragma unroll
        for (int mt = 0; mt < 4; ++mt) {
            ushort4 o = pack4(fmaxf(acc[mt][0], 0.f), fmaxf(acc[mt][1], 0.f),
                              fmaxf(acc[mt][2], 0.f), fmaxf(acc[mt][3], 0.f));
            *reinterpret_cast<ushort4*>(
                &h1u[(mt * 16 + l16) * 136 + wv * 16 + quad * 4]) = o;
        }
    }
    __syncthreads();

    // ---- stage 3: unique L2, swapped, K=128 -> uet (b64 stores) ----
    {
        float4 bv4 = *reinterpret_cast<const float4*>(&ub2[wv * 16 + quad * 4]);
        float4 ev4 = *reinterpret_cast<const float4*>(&emb[wv * 16 + quad * 4]);
        f32x4 acc[4];
        #pragma unroll
        for (int mt = 0; mt < 4; ++mt) acc[mt] = {bv4.x, bv4.y, bv4.z, bv4.w};
        bf16x8 wfc = wf3, wfn;
        #pragma unroll
        for (int kk = 0; kk < 4; ++kk) {
            if (kk < 3)
                wfn = *reinterpret_cast<const bf16x8*>(
                    &uw2b[(size_t)(wv * 16 + l16) * 128 + (kk + 1) * 32 + quad * 8]);
            #pragma unroll
            for (int mt = 0; mt < 4; ++mt) {
                bf16x8 xf = *reinterpret_cast<const bf16x8*>(
                    &h1u[(mt * 16 + l16) * 136 + kk * 32 + quad * 8]);
                acc[mt] = __builtin_amdgcn_mfma_f32_16x16x32_bf16(wfc, xf, acc[mt], 0, 0, 0);
            }
            wfc = wfn;
        }
        #pragma unroll
        for (int mt = 0; mt < 4; ++mt) {
            bool noop = (noopf[mt * 16 + l16] != 0.0f);
            ushort4 o = pack4(noop ? ev4.x : fmaxf(acc[mt][0], 0.f),
                              noop ? ev4.y : fmaxf(acc[mt][1], 0.f),
                              noop ? ev4.z : fmaxf(acc[mt][2], 0.f),
                              noop ? ev4.w : fmaxf(acc[mt][3], 0.f));
            *reinterpret_cast<ushort4*>(
                &uet[(mt * 16 + l16) * 136 + wv * 16 + quad * 4]) = o;
        }
        // deferred cse LDS write (loads issued in stage 1, latency hidden)
        ((uint32_t*)cseL)[t] = cse_r0;
        ((uint32_t*)cseL)[t + 512] = cse_r1;
    }
    __syncthreads();

    // ---- trunk: 2 N-chunks of 256; swapped L1 (acc init = cse) -> L2 ----
    f32x4 acc2[4][2];
    #pragma unroll
    for (int nt = 0; nt < 2; ++nt) {
        float4 bv4 = *reinterpret_cast<const float4*>(
            &tb2[wv * 32 + nt * 16 + quad * 4]);
        #pragma unroll
        for (int mt = 0; mt < 4; ++mt) acc2[mt][nt] = {bv4.x, bv4.y, bv4.z, bv4.w};
    }

    const uint16_t* tw1ue_base = tw1ue + (size_t)(wv * 32 + l16) * 128 + quad * 8;
    bf16x8 bc[2], bn[2];
    bc[0] = *reinterpret_cast<const bf16x8*>(tw1ue_base);
    bc[1] = *reinterpret_cast<const bf16x8*>(tw1ue_base + 2048);

    #pragma unroll
    for (int nc = 0; nc < 2; ++nc) {
        const uint16_t* bb = tw1ue_base + (size_t)nc * 32768;
        const uint16_t* cb = tw2b + (size_t)(wv * 32 + l16) * 512 + nc * 256
                             + quad * 8;
        // issue-early: this nc's L2-phase B (in flight through L1 phase)
        bf16x8 cc[2], cn[2];
        cc[0] = *reinterpret_cast<const bf16x8*>(cb);
        cc[1] = *reinterpret_cast<const bf16x8*>(cb + 8192);
        {
            f32x4 acc1[4][2];
            #pragma unroll
            for (int nt = 0; nt < 2; ++nt) {
                int n0 = nc * 256 + wv * 32 + nt * 16 + quad * 4;
                #pragma unroll
                for (int mt = 0; mt < 4; ++mt) {
                    ushort4 cv = *reinterpret_cast<const ushort4*>(
                        &cseL[mt * 512 + n0]);
                    acc1[mt][nt] = {u2f(cv.x), u2f(cv.y), u2f(cv.z), u2f(cv.w)};
                }
            }
            #pragma unroll
            for (int kk = 0; kk < 4; ++kk) {
                if (kk < 3) {
                    bn[0] = *reinterpret_cast<const bf16x8*>(bb + (kk + 1) * 32);
                    bn[1] = *reinterpret_cast<const bf16x8*>(bb + 2048 + (kk + 1) * 32);
                }
                bf16x8 af[4];
                #pragma unroll
                for (int mt = 0; mt < 4; ++mt)
                    af[mt] = *reinterpret_cast<const bf16x8*>(
                        &uet[(mt * 16 + l16) * 136 + kk * 32 + quad * 8]);
                #pragma unroll
                for (int mt = 0; mt < 4; ++mt)
                    #pragma unroll
                    for (int nt = 0; nt < 2; ++nt)
                        acc1[mt][nt] = __builtin_amdgcn_mfma_f32_16x16x32_bf16(
                            bc[nt], af[mt], acc1[mt][nt], 0, 0, 0);
                bc[0] = bn[0]; bc[1] = bn[1];
            }
            if (nc == 0) {   // issue-early: nc=1 L1 B (in flight through L2)
                bc[0] = *reinterpret_cast<const bf16x8*>(tw1ue_base + 32768);
                bc[1] = *reinterpret_cast<const bf16x8*>(tw1ue_base + 32768 + 2048);
            }
            #pragma unroll
            for (int mt = 0; mt < 4; ++mt)
                #pragma unroll
                for (int nt = 0; nt < 2; ++nt) {
                    ushort4 o = pack4(fmaxf(acc1[mt][nt][0], 0.f),
                                      fmaxf(acc1[mt][nt][1], 0.f),
                                      fmaxf(acc1[mt][nt][2], 0.f),
                                      fmaxf(acc1[mt][nt][3], 0.f));
                    *reinterpret_cast<ushort4*>(
                        &h1t[(mt * 16 + l16) * 264 + wv * 32 + nt * 16 + quad * 4]) = o;
                }
        }
        __syncthreads();
        {
            #pragma unroll
            for (int k2 = 0; k2 < 8; ++k2) {
                if (k2 < 7) {
                    cn[0] = *reinterpret_cast<const bf16x8*>(cb + (k2 + 1) * 32);
                    cn[1] = *reinterpret_cast<const bf16x8*>(cb + 8192 + (k2 + 1) * 32);
                }
                bf16x8 af[4];
                #pragma unroll
                for (int mt = 0; mt < 4; ++mt)
                    af[mt] = *reinterpret_cast<const bf16x8*>(
                        &h1t[(mt * 16 + l16) * 264 + k2 * 32 + quad * 8]);
                #pragma unroll
                for (int mt = 0; mt < 4; ++mt)
                    #pragma unroll
                    for (int nt = 0; nt < 2; ++nt)
                        acc2[mt][nt] = __builtin_amdgcn_mfma_f32_16x16x32_bf16(
                            cc[nt], af[mt], acc2[mt][nt], 0, 0, 0);
                cc[0] = cn[0]; cc[1] = cn[1];
            }
        }
        if (nc == 0) __syncthreads();
    }
    __syncthreads();                             // last h1t read done

    // ---- heads: in-register from acc2 (fp32 t, no bf16 round) ----
    {
        float svr[4] = {0.f, 0.f, 0.f, 0.f};
        float sdr[4] = {0.f, 0.f, 0.f, 0.f};
        #pragma unroll
        for (int nt = 0; nt < 2; ++nt) {
            float4 vw4 = *reinterpret_cast<const float4*>(
                &vw[wv * 32 + nt * 16 + quad * 4]);
            float4 dw4 = *reinterpret_cast<const float4*>(
                &dw[wv * 32 + nt * 16 + quad * 4]);
            #pragma unroll
            for (int mt = 0; mt < 4; ++mt) {
                float t0 = fmaxf(acc2[mt][nt][0], 0.f);
                float t1 = fmaxf(acc2[mt][nt][1], 0.f);
                float t2 = fmaxf(acc2[mt][nt][2], 0.f);
                float t3 = fmaxf(acc2[mt][nt][3], 0.f);
                svr[mt] += t0 * vw4.x + t1 * vw4.y + t2 * vw4.z + t3 * vw4.w;
                sdr[mt] += t0 * dw4.x + t1 * dw4.y + t2 * dw4.z + t3 * dw4.w;
            }
        }
        #pragma unroll
        for (int mt = 0; mt < 4; ++mt) {         // reduce over quads
            svr[mt] += __shfl_xor(svr[mt], 16);
            svr[mt] += __shfl_xor(svr[mt], 32);
            sdr[mt] += __shfl_xor(sdr[mt], 16);
            sdr[mt] += __shfl_xor(sdr[mt], 32);
        }
        if (quad == 0) {                         // stage per-wave partials
            #pragma unroll
            for (int mt = 0; mt < 4; ++mt) {
                int row = mt * 16 + l16;
                hred[(row * 2 + 0) * 8 + wv] = svr[mt];
                hred[(row * 2 + 1) * 8 + wv] = sdr[mt];
            }
        }
    }
    __syncthreads();
    if (t < 128) {                               // final reduce over 8 waves
        const float* p = &hred[t * 8];
        float s = p[0] + p[1] + p[2] + p[3] + p[4] + p[5] + p[6] + p[7];
        int row = t >> 1;
        int g = blockIdx.x * 64 + row;
        if ((t & 1) == 0) {
            out[g] = s + vb[0];
        } else {
            float z = s + db[0];
            float sig = 1.f / (1.f + __expf(-z));
            out[B_ * 16 + g] = sig * 0.4f + 0.1f;
        }
    }
}

extern "C" void kernel_launch(void* const* d_in, const int* in_sizes, int n_in,
                              void* d_out, int out_size, void* d_ws, size_t ws_size,
                              hipStream_t stream) {
    const float* obs = (const float*)d_in[0];
    const float* sw1 = (const float*)d_in[1];
    const float* sb1 = (const float*)d_in[2];
    const float* sw2 = (const float*)d_in[3];
    const float* sb2 = (const float*)d_in[4];
    const float* uw1 = (const float*)d_in[5];
    const float* ub1 = (const float*)d_in[6];
    const float* uw2 = (const float*)d_in[7];
    const float* ub2 = (const float*)d_in[8];
    const float* emb = (const float*)d_in[9];
    const float* tw1 = (const float*)d_in[10];
    const float* tb1 = (const float*)d_in[11];
    const float* tw2 = (const float*)d_in[12];
    const float* tb2 = (const float*)d_in[13];
    const float* vw  = (const float*)d_in[14];
    const float* vb  = (const float*)d_in[15];
    const float* dw  = (const float*)d_in[16];
    const float* db  = (const float*)d_in[17];

    uint16_t* wsb = (uint16_t*)d_ws;

    k_conv<<<404, 256, 0, stream>>>(tw1, tw2, uw2, sw2, uw1, wsb);
    k_cse<<<512, 512, 0, stream>>>(obs, sw1, sb1, sb2, tb1, wsb);
    k_main<<<B_ / 4, 512, 0, stream>>>(obs, ub1, ub2, emb, tb2,
                                       vw, vb, dw, db, wsb, (float*)d_out);
}